// Round 2
// baseline (761.761 us; speedup 1.0000x reference)
//
#include <hip/hip_runtime.h>
#include <float.h>

#define KCODES 512
#define GDIM 64
#define CHUNK 128
#define TAU 2.5e-3f   // > 2x worst-case per-pair f32 ordering error (~1.2e-3)

// ---- workspace layout (floats) ----
// embT : [0, 32768)        512 codes x 64 dims, transposed weight
// e2   : [32768, 33280)    per-code squared norm (f32)
// cnt  : int at float-index 33280
// list : ints from 33281   flagged (grp<<16|pos) entries, capacity 262144

// Transpose weight (64x512) -> embT (512x64), e2[k] = sum_g w[g][k]^2.
// Also zero the pass-B worklist counter (ws is poisoned 0xAA each launch).
__global__ void prep_kernel(const float* __restrict__ w,
                            float* __restrict__ embT,
                            float* __restrict__ e2,
                            int* __restrict__ cnt) {
    int k = blockIdx.x * blockDim.x + threadIdx.x;
    if (k == 0) *cnt = 0;
    if (k >= KCODES) return;
    float s = 0.0f;
    for (int g = 0; g < GDIM; ++g) {
        float v = w[g * KCODES + k];
        embT[k * GDIM + g] = v;
        s = __fadd_rn(s, __fmul_rn(v, v));
    }
    e2[k] = s;
}

// Pass A: f32 distances, 2 positions/thread, codebook chunked through LDS.
// Tracks best and second-best; near-ties (gap <= TAU) go to the worklist.
__launch_bounds__(256)
__global__ void vq_kernel(const float* __restrict__ x,
                          const float* __restrict__ embT,
                          const float* __restrict__ e2,
                          float* __restrict__ out_res,
                          float* __restrict__ out_arg,
                          int* __restrict__ cnt,
                          int* __restrict__ list) {
    __shared__ float s_emb[CHUNK * GDIM];
    __shared__ float s_e2[CHUNK];

    const int t = threadIdx.x;
    const int blk = blockIdx.x;
    const int grp = blk >> 7;
    const int pos = ((blk & 127) << 9) + (t << 1);   // even; pos,pos+1 share b
    const int b = pos >> 10;
    const int sidx = pos & 1023;

    const float* xp = x + (size_t)b * 262144 + (size_t)grp * 65536 + sidx;

    float x0[GDIM], x1[GDIM];
#pragma unroll
    for (int g = 0; g < GDIM; ++g) {
        float2 v = *(const float2*)(xp + g * 1024);
        x0[g] = v.x; x1[g] = v.y;
    }

    float a0 = 0.f, a1 = 0.f;
#pragma unroll
    for (int g = 0; g < GDIM; ++g) {
        a0 = __fadd_rn(a0, __fmul_rn(x0[g], x0[g]));
        a1 = __fadd_rn(a1, __fmul_rn(x1[g], x1[g]));
    }

    float best0 = FLT_MAX, best1 = FLT_MAX;
    float sec0 = FLT_MAX, sec1 = FLT_MAX;
    int arg0 = 0, arg1 = 0;

    for (int c = 0; c < KCODES / CHUNK; ++c) {
        __syncthreads();
        const float4* src = (const float4*)(embT + (size_t)c * CHUNK * GDIM);
        float4* dst = (float4*)s_emb;
#pragma unroll
        for (int i = 0; i < (CHUNK * GDIM / 4) / 256; ++i)
            dst[t + i * 256] = src[t + i * 256];
        if (t < CHUNK) s_e2[t] = e2[c * CHUNK + t];
        __syncthreads();

        for (int k = 0; k < CHUNK; ++k) {
            const float* ec = s_emb + k * GDIM;
            float p00 = 0.f, p01 = 0.f, p02 = 0.f, p03 = 0.f;
            float p10 = 0.f, p11 = 0.f, p12 = 0.f, p13 = 0.f;
#pragma unroll
            for (int g = 0; g < GDIM; g += 4) {
                float4 e = *(const float4*)(ec + g);   // broadcast ds_read_b128
                p00 = __fmaf_rn(x0[g + 0], e.x, p00);
                p01 = __fmaf_rn(x0[g + 1], e.y, p01);
                p02 = __fmaf_rn(x0[g + 2], e.z, p02);
                p03 = __fmaf_rn(x0[g + 3], e.w, p03);
                p10 = __fmaf_rn(x1[g + 0], e.x, p10);
                p11 = __fmaf_rn(x1[g + 1], e.y, p11);
                p12 = __fmaf_rn(x1[g + 2], e.z, p12);
                p13 = __fmaf_rn(x1[g + 3], e.w, p13);
            }
            float dot0 = (p00 + p01) + (p02 + p03);
            float dot1 = (p10 + p11) + (p12 + p13);
            float se2 = s_e2[k];
            float d0 = (a0 - (dot0 + dot0)) + se2;
            float d1 = (a1 - (dot1 + dot1)) + se2;
            int kk = c * CHUNK + k;
            if (d0 < best0) { sec0 = best0; best0 = d0; arg0 = kk; }
            else if (d0 < sec0) { sec0 = d0; }
            if (d1 < best1) { sec1 = best1; best1 = d1; arg1 = kk; }
            else if (d1 < sec1) { sec1 = d1; }
        }
    }

    // Epilogue: result = emb[:, argmin] * 0.5 (exact), coalesced float2.
    float* rp = out_res + (size_t)b * 262144 + (size_t)grp * 65536 + sidx;
    const float* e0 = embT + (size_t)arg0 * GDIM;
    const float* e1 = embT + (size_t)arg1 * GDIM;
#pragma unroll
    for (int g = 0; g < GDIM; g += 4) {
        float4 q0 = *(const float4*)(e0 + g);
        float4 q1 = *(const float4*)(e1 + g);
        float2 v;
        v.x = q0.x * 0.5f; v.y = q1.x * 0.5f; *(float2*)(rp + (g + 0) * 1024) = v;
        v.x = q0.y * 0.5f; v.y = q1.y * 0.5f; *(float2*)(rp + (g + 1) * 1024) = v;
        v.x = q0.z * 0.5f; v.y = q1.z * 0.5f; *(float2*)(rp + (g + 2) * 1024) = v;
        v.x = q0.w * 0.5f; v.y = q1.w * 0.5f; *(float2*)(rp + (g + 3) * 1024) = v;
    }

    float2 av; av.x = (float)arg0; av.y = (float)arg1;
    *(float2*)(out_arg + (size_t)b * 4096 + (size_t)grp * 1024 + sidx) = av;

    // Flag near-ties for the exact f64 pass (rare).
    if (sec0 - best0 <= TAU) { int i = atomicAdd(cnt, 1); list[i] = (grp << 16) | pos; }
    if (sec1 - best1 <= TAU) { int i = atomicAdd(cnt, 1); list[i] = (grp << 16) | (pos + 1); }
}

// Pass B: exact f64 re-scan of flagged positions. One wave per position,
// lane handles codes k = lane + 64*m. Lexicographic (d,k) reduce gives
// first-occurrence tie-break like np.argmin.
__launch_bounds__(256)
__global__ void fix_kernel(const float* __restrict__ x,
                           const float* __restrict__ embT,
                           const int* __restrict__ cnt,
                           const int* __restrict__ list,
                           float* __restrict__ out_res,
                           float* __restrict__ out_arg) {
    const int lane = threadIdx.x & 63;
    const int wave = (blockIdx.x * blockDim.x + threadIdx.x) >> 6;
    const int nwaves = (gridDim.x * blockDim.x) >> 6;
    const int n = *cnt;

    for (int i = wave; i < n; i += nwaves) {
        const int gp = list[i];
        const int grp = gp >> 16;
        const int pos = gp & 0xffff;
        const int b = pos >> 10;
        const int sidx = pos & 1023;

        const float* xp = x + (size_t)b * 262144 + (size_t)grp * 65536 + sidx;
        float xr[GDIM];
#pragma unroll
        for (int g = 0; g < GDIM; ++g) xr[g] = xp[g * 1024];  // broadcast across lanes

        double a = 0.0;
#pragma unroll
        for (int g = 0; g < GDIM; ++g) a += (double)xr[g] * (double)xr[g];

        double bd = DBL_MAX;
        int bk = 0;
        for (int m = 0; m < KCODES / 64; ++m) {
            const int k = lane + m * 64;               // ascending per lane
            const float* er = embT + (size_t)k * GDIM;
            double dot = 0.0, ee = 0.0;
#pragma unroll
            for (int g = 0; g < GDIM; g += 4) {
                float4 e4 = *(const float4*)(er + g);
                dot += (double)xr[g + 0] * (double)e4.x;
                dot += (double)xr[g + 1] * (double)e4.y;
                dot += (double)xr[g + 2] * (double)e4.z;
                dot += (double)xr[g + 3] * (double)e4.w;
                ee  += (double)e4.x * (double)e4.x;
                ee  += (double)e4.y * (double)e4.y;
                ee  += (double)e4.z * (double)e4.z;
                ee  += (double)e4.w * (double)e4.w;
            }
            double d = (a - 2.0 * dot) + ee;
            if (d < bd) { bd = d; bk = k; }            // k ascending -> first occurrence
        }
        // wave-level lexicographic min
        for (int off = 32; off > 0; off >>= 1) {
            double od = __shfl_down(bd, off, 64);
            int    ok = __shfl_down(bk, off, 64);
            if (od < bd || (od == bd && ok < bk)) { bd = od; bk = ok; }
        }
        bk = __shfl(bk, 0, 64);

        if (lane == 0)
            out_arg[(size_t)b * 4096 + (size_t)grp * 1024 + sidx] = (float)bk;
        // rewrite the 64 result values (lane = dim g)
        out_res[(size_t)b * 262144 + (size_t)grp * 65536 + (size_t)lane * 1024 + sidx] =
            embT[(size_t)bk * GDIM + lane] * 0.5f;
    }
}

extern "C" void kernel_launch(void* const* d_in, const int* in_sizes, int n_in,
                              void* d_out, int out_size, void* d_ws, size_t ws_size,
                              hipStream_t stream) {
    const float* x = (const float*)d_in[0];      // (64,256,32,32) f32
    const float* w = (const float*)d_in[1];      // (64,512) f32
    float* out_res = (float*)d_out;              // 16777216 floats
    float* out_arg = (float*)d_out + 16777216;   // 262144 floats (argmin as f32)
    float* embT = (float*)d_ws;                  // 512*64
    float* e2   = embT + KCODES * GDIM;          // 512
    int*   cnt  = (int*)(e2 + KCODES);           // 1
    int*   list = cnt + 1;                       // up to 262144

    prep_kernel<<<2, 256, 0, stream>>>(w, embT, e2, cnt);
    vq_kernel<<<512, 256, 0, stream>>>(x, embT, e2, out_res, out_arg, cnt, list);
    fix_kernel<<<256, 256, 0, stream>>>(x, embT, cnt, list, out_res, out_arg);
}

// Round 3
// 493.049 us; speedup vs baseline: 1.5450x; 1.5450x over previous
//
#include <hip/hip_runtime.h>
#include <float.h>

#define KCODES 512
#define GDIM 64
#define CHUNK 128
#define TAU 2.0e-3f   // flag gap threshold on s = e2 - 2*dot (same scale as d-gaps)

// ---- workspace layout (floats) ----
// embT : [0, 32768)        512 codes x 64 dims, transposed weight
// e2   : [32768, 33280)    per-code squared norm
// cnt  : int at float-index 33280
// list : ints from 33281   flagged (grp<<16|pos), capacity 262144

__global__ void prep_kernel(const float* __restrict__ w,
                            float* __restrict__ embT,
                            float* __restrict__ e2,
                            int* __restrict__ cnt) {
    int k = blockIdx.x * blockDim.x + threadIdx.x;
    if (k == 0) *cnt = 0;
    if (k >= KCODES) return;
    float s = 0.0f;
    for (int g = 0; g < GDIM; ++g) {
        float v = w[g * KCODES + k];
        embT[k * GDIM + g] = v;
        s = __fadd_rn(s, __fmul_rn(v, v));
    }
    e2[k] = s;
}

// Pass A: 1 position per thread (x = 64 VGPRs), codebook chunked through LDS.
// s = e2 - 2*dot ranks identically to the full distance (a is per-position
// constant); near-ties (gap <= TAU) go to the exact-f64 worklist.
// launch_bounds(256,4): cap VGPRs at 128 so 4 waves/SIMD are resident and the
// compiler has ~50 spare regs to batch the 16 e-loads per k (round-2 failure
// mode: 8 spare regs -> fully serialized ds_read latency, 3300 cyc/k).
__launch_bounds__(256, 4)
__global__ void vq_kernel(const float* __restrict__ x,
                          const float* __restrict__ embT,
                          const float* __restrict__ e2,
                          float* __restrict__ out_res,
                          float* __restrict__ out_arg,
                          int* __restrict__ cnt,
                          int* __restrict__ list) {
    __shared__ float s_emb[CHUNK * GDIM];
    __shared__ float s_e2[CHUNK];

    const int t = threadIdx.x;
    const int blk = blockIdx.x;
    const int grp = blk >> 8;                     // 256 blocks per group
    const int pos = ((blk & 255) << 8) + t;       // 0..65535 within group
    const int b = pos >> 10;
    const int sidx = pos & 1023;

    const float* xp = x + (size_t)b * 262144 + (size_t)grp * 65536 + sidx;

    float xr[GDIM];
#pragma unroll
    for (int g = 0; g < GDIM; ++g) xr[g] = xp[g * 1024];   // coalesced dword

    float best = FLT_MAX, sec = FLT_MAX;
    int arg = 0;

    for (int c = 0; c < KCODES / CHUNK; ++c) {
        __syncthreads();
        const float4* src = (const float4*)(embT + (size_t)c * CHUNK * GDIM);
        float4* dst = (float4*)s_emb;
#pragma unroll
        for (int i = 0; i < (CHUNK * GDIM / 4) / 256; ++i)
            dst[t + i * 256] = src[t + i * 256];
        if (t < CHUNK) s_e2[t] = e2[c * CHUNK + t];
        __syncthreads();

        for (int k = 0; k < CHUNK; ++k) {
            const float* ec = s_emb + k * GDIM;
            float p0 = 0.f, p1 = 0.f, p2 = 0.f, p3 = 0.f;
#pragma unroll
            for (int g = 0; g < GDIM; g += 4) {
                float4 e = *(const float4*)(ec + g);   // broadcast ds_read_b128
                p0 = __fmaf_rn(xr[g + 0], e.x, p0);
                p1 = __fmaf_rn(xr[g + 1], e.y, p1);
                p2 = __fmaf_rn(xr[g + 2], e.z, p2);
                p3 = __fmaf_rn(xr[g + 3], e.w, p3);
            }
            float dot = (p0 + p1) + (p2 + p3);
            float s = __fmaf_rn(-2.0f, dot, s_e2[k]);
            int kk = c * CHUNK + k;
            if (s < best) { sec = best; best = s; arg = kk; }
            else if (s < sec) { sec = s; }
        }
    }

    // Epilogue: result = emb[:, argmin] * 0.5 (exact). Stores coalesced dword.
    float* rp = out_res + (size_t)b * 262144 + (size_t)grp * 65536 + sidx;
    const float* ev = embT + (size_t)arg * GDIM;
#pragma unroll
    for (int g = 0; g < GDIM; g += 4) {
        float4 q = *(const float4*)(ev + g);           // L2-hot, 16B
        rp[(g + 0) * 1024] = q.x * 0.5f;
        rp[(g + 1) * 1024] = q.y * 0.5f;
        rp[(g + 2) * 1024] = q.z * 0.5f;
        rp[(g + 3) * 1024] = q.w * 0.5f;
    }
    out_arg[(size_t)b * 4096 + (size_t)grp * 1024 + sidx] = (float)arg;

    if (sec - best <= TAU) { int i = atomicAdd(cnt, 1); list[i] = (grp << 16) | pos; }
}

// Pass B: exact f64 re-scan of flagged positions (unchanged from round 2 —
// verified correct). One wave per position; lexicographic (d,k) reduce.
__launch_bounds__(256)
__global__ void fix_kernel(const float* __restrict__ x,
                           const float* __restrict__ embT,
                           const int* __restrict__ cnt,
                           const int* __restrict__ list,
                           float* __restrict__ out_res,
                           float* __restrict__ out_arg) {
    const int lane = threadIdx.x & 63;
    const int wave = (blockIdx.x * blockDim.x + threadIdx.x) >> 6;
    const int nwaves = (gridDim.x * blockDim.x) >> 6;
    const int n = *cnt;

    for (int i = wave; i < n; i += nwaves) {
        const int gp = list[i];
        const int grp = gp >> 16;
        const int pos = gp & 0xffff;
        const int b = pos >> 10;
        const int sidx = pos & 1023;

        const float* xp = x + (size_t)b * 262144 + (size_t)grp * 65536 + sidx;
        float xr[GDIM];
#pragma unroll
        for (int g = 0; g < GDIM; ++g) xr[g] = xp[g * 1024];

        double a = 0.0;
#pragma unroll
        for (int g = 0; g < GDIM; ++g) a += (double)xr[g] * (double)xr[g];

        double bd = DBL_MAX;
        int bk = 0;
        for (int m = 0; m < KCODES / 64; ++m) {
            const int k = lane + m * 64;
            const float* er = embT + (size_t)k * GDIM;
            double dot = 0.0, ee = 0.0;
#pragma unroll
            for (int g = 0; g < GDIM; g += 4) {
                float4 e4 = *(const float4*)(er + g);
                dot += (double)xr[g + 0] * (double)e4.x;
                dot += (double)xr[g + 1] * (double)e4.y;
                dot += (double)xr[g + 2] * (double)e4.z;
                dot += (double)xr[g + 3] * (double)e4.w;
                ee  += (double)e4.x * (double)e4.x;
                ee  += (double)e4.y * (double)e4.y;
                ee  += (double)e4.z * (double)e4.z;
                ee  += (double)e4.w * (double)e4.w;
            }
            double d = (a - 2.0 * dot) + ee;
            if (d < bd) { bd = d; bk = k; }
        }
        for (int off = 32; off > 0; off >>= 1) {
            double od = __shfl_down(bd, off, 64);
            int    ok = __shfl_down(bk, off, 64);
            if (od < bd || (od == bd && ok < bk)) { bd = od; bk = ok; }
        }
        bk = __shfl(bk, 0, 64);

        if (lane == 0)
            out_arg[(size_t)b * 4096 + (size_t)grp * 1024 + sidx] = (float)bk;
        out_res[(size_t)b * 262144 + (size_t)grp * 65536 + (size_t)lane * 1024 + sidx] =
            embT[(size_t)bk * GDIM + lane] * 0.5f;
    }
}

extern "C" void kernel_launch(void* const* d_in, const int* in_sizes, int n_in,
                              void* d_out, int out_size, void* d_ws, size_t ws_size,
                              hipStream_t stream) {
    const float* x = (const float*)d_in[0];      // (64,256,32,32) f32
    const float* w = (const float*)d_in[1];      // (64,512) f32
    float* out_res = (float*)d_out;              // 16777216 floats
    float* out_arg = (float*)d_out + 16777216;   // 262144 floats
    float* embT = (float*)d_ws;
    float* e2   = embT + KCODES * GDIM;
    int*   cnt  = (int*)(e2 + KCODES);
    int*   list = cnt + 1;

    prep_kernel<<<2, 256, 0, stream>>>(w, embT, e2, cnt);
    vq_kernel<<<1024, 256, 0, stream>>>(x, embT, e2, out_res, out_arg, cnt, list);
    fix_kernel<<<256, 256, 0, stream>>>(x, embT, cnt, list, out_res, out_arg);
}